// Round 1
// baseline (187.736 us; speedup 1.0000x reference)
//
#include <hip/hip_runtime.h>

#define BB 2
#define LL 16
#define CC 16
#define HH 64
#define WW 64
#define HWSZ (HH * WW)

__global__ __launch_bounds__(256) void gsp_kernel(
    const float* __restrict__ flows,   // (B, L, 2, H, W)
    const float* __restrict__ images,  // (B, L, C, H, W)
    float* __restrict__ out)           // (B, L, C, H, W)
{
    const int blocksPerImage = HWSZ / 256;            // 16
    const int bi   = blockIdx.x / blocksPerImage;     // 0..B*L-1
    const int tile = blockIdx.x % blocksPerImage;
    const int b = bi / LL;
    const int i = bi % LL;
    const int pix = tile * 256 + threadIdx.x;         // 0..4095
    const int h = pix >> 6;
    const int w = pix & (WW - 1);

    const float* img_b  = images + (size_t)b * LL * CC * HWSZ;
    const float* flow_b = flows  + (size_t)b * LL * 2  * HWSZ;

    // j == i term: rel = 0 -> exact integer pixel sample (wx = wy = 0 exactly)
    float acc[CC];
    {
        const float* p = img_b + (size_t)i * CC * HWSZ + pix;
        #pragma unroll
        for (int c = 0; c < CC; ++c) acc[c] = p[c * HWSZ];
    }

    const float gxb = (w + 0.5f) * (2.0f / WW) - 1.0f;
    const float gyb = (h + 0.5f) * (2.0f / HH) - 1.0f;

    float relx = 0.0f, rely = 0.0f;
    for (int j = i - 1; j >= 0; --j) {
        // rel[i,j] = cum[i] - cum[j] = sum_{t=j+1..i} flows[t]
        relx += flow_b[(size_t)(j + 1) * 2 * HWSZ + pix];
        rely += flow_b[(size_t)(j + 1) * 2 * HWSZ + HWSZ + pix];

        float gx = gxb + relx;
        float gy = gyb + rely;

        // gx = remainder(gx + 1, 2) - 1   (sign of divisor, i.e. result in [0,2))
        float t = gx + 1.0f;
        t = t - floorf(t * 0.5f) * 2.0f;
        gx = t - 1.0f;

        const float ix = ((gx + 1.0f) * WW - 1.0f) * 0.5f;
        const float iy = ((gy + 1.0f) * HH - 1.0f) * 0.5f;
        const float x0f = floorf(ix);
        const float y0f = floorf(iy);
        const float wx = ix - x0f;
        const float wy = iy - y0f;
        const int x0 = (int)x0f;
        const int y0 = (int)y0f;
        const int x1 = x0 + 1;
        const int y1 = y0 + 1;

        const bool vx0 = (x0 >= 0) && (x0 < WW);
        const bool vx1 = (x1 >= 0) && (x1 < WW);
        const bool vy0 = (y0 >= 0) && (y0 < HH);
        const bool vy1 = (y1 >= 0) && (y1 < HH);

        const int cx0 = min(max(x0, 0), WW - 1);
        const int cx1 = min(max(x1, 0), WW - 1);
        const int cy0 = min(max(y0, 0), HH - 1);
        const int cy1 = min(max(y1, 0), HH - 1);

        const float w00 = (1.0f - wx) * (1.0f - wy) * ((vx0 && vy0) ? 1.0f : 0.0f);
        const float w01 = wx * (1.0f - wy)          * ((vx1 && vy0) ? 1.0f : 0.0f);
        const float w10 = (1.0f - wx) * wy          * ((vx0 && vy1) ? 1.0f : 0.0f);
        const float w11 = wx * wy                   * ((vx1 && vy1) ? 1.0f : 0.0f);

        const int o00 = cy0 * WW + cx0;
        const int o01 = cy0 * WW + cx1;
        const int o10 = cy1 * WW + cx0;
        const int o11 = cy1 * WW + cx1;

        const float* ib = img_b + (size_t)j * CC * HWSZ;
        #pragma unroll
        for (int c = 0; c < CC; ++c) {
            const float* p = ib + c * HWSZ;
            acc[c] += w00 * p[o00] + w01 * p[o01] + w10 * p[o10] + w11 * p[o11];
        }
    }

    float* op = out + (size_t)bi * CC * HWSZ + pix;
    #pragma unroll
    for (int c = 0; c < CC; ++c) op[c * HWSZ] = acc[c];
}

extern "C" void kernel_launch(void* const* d_in, const int* in_sizes, int n_in,
                              void* d_out, int out_size, void* d_ws, size_t ws_size,
                              hipStream_t stream) {
    const float* flows  = (const float*)d_in[0];
    const float* images = (const float*)d_in[1];
    float* out = (float*)d_out;

    const int grid = BB * LL * (HWSZ / 256);  // 512 blocks
    gsp_kernel<<<grid, 256, 0, stream>>>(flows, images, out);
}

// Round 2
// 134.779 us; speedup vs baseline: 1.3929x; 1.3929x over previous
//
#include <hip/hip_runtime.h>

#define BB 2
#define LL 16
#define CC 16
#define HH 64
#define WW 64
#define HWSZ (HH * WW)
#define NSEG 36   // j-segments of width 4 over j in [0, i-1], for i = 1..15

// segment tables: (i, j0) pairs; j range is [j0, min(j0+3, i-1)]
__device__ __constant__ int SEG_I[NSEG] = {
    1, 2, 3, 4,
    5, 5, 6, 6, 7, 7, 8, 8,
    9, 9, 9, 10, 10, 10, 11, 11, 11, 12, 12, 12,
    13, 13, 13, 13, 14, 14, 14, 14, 15, 15, 15, 15};
__device__ __constant__ int SEG_J0[NSEG] = {
    0, 0, 0, 0,
    0, 4, 0, 4, 0, 4, 0, 4,
    0, 4, 8, 0, 4, 8, 0, 4, 8, 0, 4, 8,
    0, 4, 8, 12, 0, 4, 8, 12, 0, 4, 8, 12};

// identity term (j == i samples at exact pixel centers): out = images, float4 copy
__global__ __launch_bounds__(256) void gsp_identity(
    const float4* __restrict__ images, float4* __restrict__ out)
{
    const int idx = blockIdx.x * 256 + threadIdx.x;   // n = 524288 exactly
    out[idx] = images[idx];
}

__global__ __launch_bounds__(256) void gsp_seg(
    const float* __restrict__ flows,   // (B, L, 2, H, W)
    const float* __restrict__ images,  // (B, L, C, H, W)
    float* __restrict__ out)           // (B, L, C, H, W)
{
    const int tile = blockIdx.x & 15;            // 16 tiles of 256 pixels
    const int seg  = (blockIdx.x >> 4) % NSEG;
    const int b    = blockIdx.x / (16 * NSEG);

    const int i  = SEG_I[seg];
    const int j0 = SEG_J0[seg];
    const int j1 = min(j0 + 3, i - 1);

    const int pix = tile * 256 + threadIdx.x;    // 0..4095
    const int h = pix >> 6;
    const int w = pix & (WW - 1);

    const float* img_b  = images + (size_t)b * LL * CC * HWSZ;
    const float* flow_b = flows  + (size_t)b * LL * 2  * HWSZ;

    float acc[CC];
    #pragma unroll
    for (int c = 0; c < CC; ++c) acc[c] = 0.0f;

    const float gxb = (w + 0.5f) * (2.0f / WW) - 1.0f;
    const float gyb = (h + 0.5f) * (2.0f / HH) - 1.0f;

    // rel[i,j] = sum_{t=j+1..i} flows[t]; walk t downward, sample when j=t-1 in [j0,j1]
    float relx = 0.0f, rely = 0.0f;
    for (int t = i; t > j0; --t) {
        relx += flow_b[(size_t)t * 2 * HWSZ + pix];
        rely += flow_b[(size_t)t * 2 * HWSZ + HWSZ + pix];
        const int j = t - 1;
        if (j > j1) continue;

        float gx = gxb + relx;
        float gy = gyb + rely;

        // gx = remainder(gx + 1, 2) - 1  (result in [0,2) before shift)
        float tt = gx + 1.0f;
        tt = tt - floorf(tt * 0.5f) * 2.0f;
        gx = tt - 1.0f;

        const float ix = ((gx + 1.0f) * WW - 1.0f) * 0.5f;
        const float iy = ((gy + 1.0f) * HH - 1.0f) * 0.5f;
        const float x0f = floorf(ix);
        const float y0f = floorf(iy);
        const float wx = ix - x0f;
        const float wy = iy - y0f;
        const int x0 = (int)x0f;
        const int y0 = (int)y0f;
        const int x1 = x0 + 1;
        const int y1 = y0 + 1;

        const bool vx0 = (x0 >= 0) && (x0 < WW);
        const bool vx1 = (x1 >= 0) && (x1 < WW);
        const bool vy0 = (y0 >= 0) && (y0 < HH);
        const bool vy1 = (y1 >= 0) && (y1 < HH);

        const int cx0 = min(max(x0, 0), WW - 1);
        const int cx1 = min(max(x1, 0), WW - 1);
        const int cy0 = min(max(y0, 0), HH - 1);
        const int cy1 = min(max(y1, 0), HH - 1);

        const float w00 = (1.0f - wx) * (1.0f - wy) * ((vx0 && vy0) ? 1.0f : 0.0f);
        const float w01 = wx * (1.0f - wy)          * ((vx1 && vy0) ? 1.0f : 0.0f);
        const float w10 = (1.0f - wx) * wy          * ((vx0 && vy1) ? 1.0f : 0.0f);
        const float w11 = wx * wy                   * ((vx1 && vy1) ? 1.0f : 0.0f);

        const int o00 = cy0 * WW + cx0;
        const int o01 = cy0 * WW + cx1;
        const int o10 = cy1 * WW + cx0;
        const int o11 = cy1 * WW + cx1;

        const float* ib = img_b + (size_t)j * CC * HWSZ;
        #pragma unroll
        for (int c = 0; c < CC; ++c) {
            const float* p = ib + c * HWSZ;
            acc[c] += w00 * p[o00] + w01 * p[o01] + w10 * p[o10] + w11 * p[o11];
        }
    }

    float* op = out + ((size_t)b * LL + i) * CC * HWSZ + pix;
    #pragma unroll
    for (int c = 0; c < CC; ++c) atomicAdd(op + c * HWSZ, acc[c]);
}

extern "C" void kernel_launch(void* const* d_in, const int* in_sizes, int n_in,
                              void* d_out, int out_size, void* d_ws, size_t ws_size,
                              hipStream_t stream) {
    const float* flows  = (const float*)d_in[0];
    const float* images = (const float*)d_in[1];
    float* out = (float*)d_out;

    // 1) init out with the j==i identity term (exact integer-center samples)
    const int n4 = BB * LL * CC * HWSZ / 4;          // 524288 float4s
    gsp_identity<<<n4 / 256, 256, 0, stream>>>((const float4*)images, (float4*)out);

    // 2) accumulate all j < i contributions, one block per (b, seg, tile)
    const int grid = BB * NSEG * 16;                 // 1152 blocks
    gsp_seg<<<grid, 256, 0, stream>>>(flows, images, out);
}